// Round 4
// baseline (356.801 us; speedup 1.0000x reference)
//
#include <hip/hip_runtime.h>
#include <stdint.h>

#define M_TOK 512
#define N_OUT 11008
#define K_IN  4096
#define BM 128
#define BN 128
#define BK 64
#define KSPLIT_LEN 2048

typedef __bf16 bf16x8 __attribute__((ext_vector_type(8)));
typedef float  f32x4  __attribute__((ext_vector_type(4)));

// ---- conversions -----------------------------------------------------------
__device__ __forceinline__ uint32_t bf_rne(float f) {
  uint32_t u = __float_as_uint(f);
  return (u + 0x7FFFu + ((u >> 16) & 1u)) >> 16;
}
__device__ __forceinline__ uint32_t pk_f(float a, float b) {
  return bf_rne(a) | (bf_rne(b) << 16);
}
__device__ __forceinline__ uint32_t pk_i(int a, int b) {
  // ints in [-127,127] are exactly representable in bf16 -> truncation is exact
  return (__float_as_uint((float)a) >> 16) | (__float_as_uint((float)b) & 0xFFFF0000u);
}

// ---- x f32 -> bf16 pre-pass -------------------------------------------------
__global__ void xcvt_kernel(const float4* __restrict__ x, uint4* __restrict__ o) {
  int i = blockIdx.x * blockDim.x + threadIdx.x;
  float4 a = x[2 * i];
  float4 b = x[2 * i + 1];
  uint4 h;
  h.x = pk_f(a.x, a.y);
  h.y = pk_f(a.z, a.w);
  h.z = pk_f(b.x, b.y);
  h.w = pk_f(b.z, b.w);
  o[i] = h;
}

// ---- reduce: out += p1 ------------------------------------------------------
__global__ void reduce_kernel(float4* __restrict__ out, const float4* __restrict__ p, int n4) {
  int i = blockIdx.x * blockDim.x + threadIdx.x;
  int stride = gridDim.x * blockDim.x;
  for (; i < n4; i += stride) {
    float4 a = out[i];
    float4 b = p[i];
    a.x += b.x; a.y += b.y; a.z += b.z; a.w += b.w;
    out[i] = a;
  }
}

// ---- LDS layout -------------------------------------------------------------
// Tile [row][64 bf16] = 128B rows, 8 chunks of 16B. Chunk c of row r stored at
// chunk (c ^ (r&7)) -> Latin-square XOR swizzle (G4).

// A tile via global_load_lds (LDS dest linear, swizzle applied on global src)
__device__ __forceinline__ void a_gload(const uint16_t* __restrict__ xb, int bm0, int kbase,
                                        uint16_t* as, int wid, int lane) {
#pragma unroll
  for (int it = 0; it < 4; ++it) {
    int s = wid * 4 + it;              // 16 segments of 1KB (8 rows each)
    int row = s * 8 + (lane >> 3);
    int gch = (lane & 7) ^ (row & 7);  // inverse-swizzled source chunk
    const uint16_t* g = xb + (size_t)(bm0 + row) * K_IN + kbase + gch * 8;
    __builtin_amdgcn_global_load_lds((const __attribute__((address_space(1))) void*)g,
                                     (__attribute__((address_space(3))) void*)&as[s * 512],
                                     16, 0, 0);
  }
}

// B (W) staging: fully-packed coalescing. 2048 chunks of 16B (4 ints);
// c = tid + i*256: row = c>>4, pos = c&15. 16 lanes cover a full 256B row
// window -> every 64B sector fully used.
__device__ __forceinline__ void b_load(const int* __restrict__ qw, int bn0, int kbase,
                                       int tid, int4* wr) {
#pragma unroll
  for (int i = 0; i < 8; ++i) {
    int c = tid + i * 256;
    int row = c >> 4;
    int pos = c & 15;
    wr[i] = *(const int4*)(qw + (size_t)(bn0 + row) * K_IN + kbase + pos * 4);
  }
}

__device__ __forceinline__ void b_write(uint16_t* bs, const int4* wr, int tid) {
#pragma unroll
  for (int i = 0; i < 8; ++i) {
    int c = tid + i * 256;
    int row = c >> 4;
    int pos = c & 15;
    uint32_t h0 = pk_i(wr[i].x, wr[i].y);
    uint32_t h1 = pk_i(wr[i].z, wr[i].w);
    int sch = (pos >> 1) ^ (row & 7);
    uint32_t* d = (uint32_t*)&bs[row * 64 + sch * 8 + (pos & 1) * 4];
    d[0] = h0;
    d[1] = h1;
  }
}

// A staging fallback (no workspace): f32 -> bf16 in-kernel
__device__ __forceinline__ void a_stage_f32(const float* __restrict__ xf, int bm0, int kbase,
                                            int tid, uint16_t* as) {
#pragma unroll
  for (int i = 0; i < 4; ++i) {
    int cid = tid + i * 256;
    int row = cid >> 3;
    int seg = cid & 7;
    const float4* g = (const float4*)(xf + (size_t)(bm0 + row) * K_IN + kbase + seg * 8);
    float4 v0 = g[0], v1 = g[1];
    uint4 h;
    h.x = pk_f(v0.x, v0.y);
    h.y = pk_f(v0.z, v0.w);
    h.z = pk_f(v1.x, v1.y);
    h.w = pk_f(v1.z, v1.w);
    int ch = seg ^ (row & 7);
    *(uint4*)&as[row * 64 + ch * 8] = h;
  }
}

// ---- GEMM ------------------------------------------------------------------
// 256 threads = 4 waves (2x2), each wave owns 64x64 = 4x4 frags of 16x16.
// SINGLE-buffered LDS (32KB) -> 4-5 blocks/CU; inter-block overlap hides the
// stage latency (m97/m114 recipe). Next-tile B loads issued under compute.
template <bool USE_WS, bool SPLIT>
__global__ __launch_bounds__(256, 4)
void qgemm(const uint16_t* __restrict__ xb, const float* __restrict__ xf,
           const int* __restrict__ qw, const float* __restrict__ scale,
           const float* __restrict__ bias, float* __restrict__ out,
           float* __restrict__ part) {
  __shared__ uint16_t As[BM * BK];  // 16KB
  __shared__ uint16_t Bs[BN * BK];  // 16KB

  const int tid = threadIdx.x;
  const int lane = tid & 63;
  const int wid = tid >> 6;
  const int wm = wid >> 1, wn = wid & 1;

  // XCD-aware mapping (bijective: grid % 8 == 0 in both modes).
  int nt, mt, ks;
  if constexpr (SPLIT) {
    // grid 688 = 8 * 86; 8 consecutive g's = one W panel (4 mt x 2 ks) per XCD
    const int xcd = blockIdx.x & 7;
    const int g = xcd * 86 + (blockIdx.x >> 3);
    nt = g >> 3;
    const int r = g & 7;
    ks = r >> 2;
    mt = r & 3;
  } else {
    // grid 344 = 8 * 43
    const int xcd = blockIdx.x & 7;
    const int g = xcd * 43 + (blockIdx.x >> 3);
    nt = g >> 2;
    mt = g & 3;
    ks = 0;
  }
  const int bm0 = mt * BM, bn0 = nt * BN;
  const int kbase0 = ks * KSPLIT_LEN;
  const int NIT = SPLIT ? (KSPLIT_LEN / BK) : (K_IN / BK);

  f32x4 acc[4][4] = {};
  int4 wreg[8];

  // prologue: issue B loads for tile 0
  b_load(qw, bn0, kbase0, tid, wreg);

  for (int t = 0; t < NIT; ++t) {
    const int kb = kbase0 + t * BK;
    if (t) __syncthreads();  // WAR: previous compute done reading LDS

    // ---- stage phase ----
    if constexpr (USE_WS) {
      a_gload(xb, bm0, kb, As, wid, lane);
    } else {
      a_stage_f32(xf, bm0, kb, tid, As);
    }
    b_write(Bs, wreg, tid);  // waits (counted) on wreg's loads only
    __syncthreads();         // drain: LDS tile ready

    // issue next tile's B loads; latency rides under the MFMA phase (T14)
    if (t + 1 < NIT) b_load(qw, bn0, kb + BK, tid, wreg);

    // ---- compute phase ----
    const int kq = lane >> 4;
#pragma unroll
    for (int kk = 0; kk < 2; ++kk) {
      bf16x8 a[4], b[4];
#pragma unroll
      for (int mi = 0; mi < 4; ++mi) {
        int row = wm * 64 + mi * 16 + (lane & 15);
        int ch = (kk * 4 + kq) ^ (row & 7);
        a[mi] = *(const bf16x8*)&As[row * 64 + ch * 8];
      }
#pragma unroll
      for (int ni = 0; ni < 4; ++ni) {
        int row = wn * 64 + ni * 16 + (lane & 15);
        int ch = (kk * 4 + kq) ^ (row & 7);
        b[ni] = *(const bf16x8*)&Bs[row * 64 + ch * 8];
      }
      __builtin_amdgcn_s_setprio(1);
#pragma unroll
      for (int mi = 0; mi < 4; ++mi)
#pragma unroll
        for (int ni = 0; ni < 4; ++ni)
          acc[mi][ni] = __builtin_amdgcn_mfma_f32_16x16x32_bf16(a[mi], b[ni], acc[mi][ni], 0, 0, 0);
      __builtin_amdgcn_s_setprio(0);
    }
  }

  // ---- epilogue ----
  float* dst = out;
  float badd = 1.0f;
  if constexpr (SPLIT) {
    if (ks == 1) { dst = part; badd = 0.0f; }
  }
  const int kq = lane >> 4;
#pragma unroll
  for (int ni = 0; ni < 4; ++ni) {
    int col = bn0 + wn * 64 + ni * 16 + (lane & 15);
    float sc = scale[col];
    float bi = bias[col] * badd;
#pragma unroll
    for (int mi = 0; mi < 4; ++mi) {
      int rowb = bm0 + wm * 64 + mi * 16 + kq * 4;
#pragma unroll
      for (int r = 0; r < 4; ++r) {
        dst[(size_t)(rowb + r) * N_OUT + col] = acc[mi][ni][r] * sc + bi;
      }
    }
  }
}

// ---- launch ----------------------------------------------------------------
extern "C" void kernel_launch(void* const* d_in, const int* in_sizes, int n_in,
                              void* d_out, int out_size, void* d_ws, size_t ws_size,
                              hipStream_t stream) {
  const float* x = (const float*)d_in[0];
  const int* qw = (const int*)d_in[1];
  const float* scale = (const float*)d_in[2];
  const float* bias = (const float*)d_in[3];
  float* out = (float*)d_out;

  const size_t xb_bytes = (size_t)M_TOK * K_IN * sizeof(uint16_t);   // 4 MB
  const size_t part_bytes = (size_t)M_TOK * N_OUT * sizeof(float);   // 22.5 MB
  const int n4 = M_TOK * N_OUT / 4;

  if (ws_size >= xb_bytes + part_bytes) {
    uint16_t* xb = (uint16_t*)d_ws;
    float* part = (float*)((char*)d_ws + xb_bytes);
    xcvt_kernel<<<1024, 256, 0, stream>>>((const float4*)x, (uint4*)xb);
    qgemm<true, true><<<dim3(688), dim3(256), 0, stream>>>(xb, x, qw, scale, bias, out, part);
    reduce_kernel<<<dim3(2048), dim3(256), 0, stream>>>((float4*)out, (const float4*)part, n4);
  } else if (ws_size >= xb_bytes) {
    uint16_t* xb = (uint16_t*)d_ws;
    xcvt_kernel<<<1024, 256, 0, stream>>>((const float4*)x, (uint4*)xb);
    qgemm<true, false><<<dim3(344), dim3(256), 0, stream>>>(xb, x, qw, scale, bias, out, nullptr);
  } else {
    qgemm<false, false><<<dim3(344), dim3(256), 0, stream>>>(nullptr, x, qw, scale, bias, out, nullptr);
  }
}

// Round 5
// 105.218 us; speedup vs baseline: 3.3911x; 3.3911x over previous
//
#include <hip/hip_runtime.h>
#include <stdint.h>

#define M_TOK 512
#define N_OUT 11008
#define K_IN  4096
#define BM 128
#define BN 128
#define BK 64
#define KSPLIT_LEN 2048

typedef __bf16 bf16x8 __attribute__((ext_vector_type(8)));
typedef float  f32x4  __attribute__((ext_vector_type(4)));

// ---- conversions -----------------------------------------------------------
__device__ __forceinline__ uint32_t bf_rne(float f) {
  uint32_t u = __float_as_uint(f);
  return (u + 0x7FFFu + ((u >> 16) & 1u)) >> 16;
}
__device__ __forceinline__ uint32_t pk_f(float a, float b) {
  return bf_rne(a) | (bf_rne(b) << 16);
}
__device__ __forceinline__ uint32_t pk_i(int a, int b) {
  // ints in [-127,127] are exactly representable in bf16 -> truncation is exact
  return (__float_as_uint((float)a) >> 16) | (__float_as_uint((float)b) & 0xFFFF0000u);
}

// ---- x f32 -> bf16 pre-pass -------------------------------------------------
__global__ void xcvt_kernel(const float4* __restrict__ x, uint4* __restrict__ o) {
  int i = blockIdx.x * blockDim.x + threadIdx.x;
  float4 a = x[2 * i];
  float4 b = x[2 * i + 1];
  uint4 h;
  h.x = pk_f(a.x, a.y);
  h.y = pk_f(a.z, a.w);
  h.z = pk_f(b.x, b.y);
  h.w = pk_f(b.z, b.w);
  o[i] = h;
}

// ---- reduce: out += p1 ------------------------------------------------------
__global__ void reduce_kernel(float4* __restrict__ out, const float4* __restrict__ p, int n4) {
  int i = blockIdx.x * blockDim.x + threadIdx.x;
  int stride = gridDim.x * blockDim.x;
  for (; i < n4; i += stride) {
    float4 a = out[i];
    float4 b = p[i];
    a.x += b.x; a.y += b.y; a.z += b.z; a.w += b.w;
    out[i] = a;
  }
}

// ---- LDS layout -------------------------------------------------------------
// Tile [row][64 bf16] = 128B rows, 8 chunks of 16B. Chunk c of row r stored at
// chunk (c ^ (r&7)) -> Latin-square XOR swizzle (G4). Verified conflict-free
// (SQ_LDS_BANK_CONFLICT = 0 in rounds 2-3).

// A tile via global_load_lds (LDS dest linear, swizzle applied on global src)
__device__ __forceinline__ void a_gload(const uint16_t* __restrict__ xb, int bm0, int kbase,
                                        uint16_t* as, int wid, int lane) {
#pragma unroll
  for (int it = 0; it < 4; ++it) {
    int s = wid * 4 + it;              // 16 segments of 1KB (8 rows each)
    int row = s * 8 + (lane >> 3);
    int gch = (lane & 7) ^ (row & 7);  // inverse-swizzled source chunk
    const uint16_t* g = xb + (size_t)(bm0 + row) * K_IN + kbase + gch * 8;
    __builtin_amdgcn_global_load_lds((const __attribute__((address_space(1))) void*)g,
                                     (__attribute__((address_space(3))) void*)&as[s * 512],
                                     16, 0, 0);
  }
}

// B (W) staging: fully-packed coalescing. 2048 chunks of 16B (4 ints);
// c = tid + i*256: row = c>>4, pos = c&15. 16 lanes cover a full 256B row
// window -> every 64B sector fully used.
__device__ __forceinline__ void b_load(const int* __restrict__ qw, int bn0, int kbase,
                                       int tid, int4* wr) {
#pragma unroll
  for (int i = 0; i < 8; ++i) {
    int c = tid + i * 256;
    int row = c >> 4;
    int pos = c & 15;
    wr[i] = *(const int4*)(qw + (size_t)(bn0 + row) * K_IN + kbase + pos * 4);
  }
}

__device__ __forceinline__ void b_write(uint16_t* bs, const int4* wr, int tid) {
#pragma unroll
  for (int i = 0; i < 8; ++i) {
    int c = tid + i * 256;
    int row = c >> 4;
    int pos = c & 15;
    uint2 h;
    h.x = pk_i(wr[i].x, wr[i].y);
    h.y = pk_i(wr[i].z, wr[i].w);
    int sch = (pos >> 1) ^ (row & 7);
    *(uint2*)&bs[row * 64 + sch * 8 + (pos & 1) * 4] = h;  // single ds_write_b64
  }
}

// A staging fallback (no workspace): f32 -> bf16 in-kernel
__device__ __forceinline__ void a_stage_f32(const float* __restrict__ xf, int bm0, int kbase,
                                            int tid, uint16_t* as) {
#pragma unroll
  for (int i = 0; i < 4; ++i) {
    int cid = tid + i * 256;
    int row = cid >> 3;
    int seg = cid & 7;
    const float4* g = (const float4*)(xf + (size_t)(bm0 + row) * K_IN + kbase + seg * 8);
    float4 v0 = g[0], v1 = g[1];
    uint4 h;
    h.x = pk_f(v0.x, v0.y);
    h.y = pk_f(v0.z, v0.w);
    h.z = pk_f(v1.x, v1.y);
    h.w = pk_f(v1.z, v1.w);
    int ch = seg ^ (row & 7);
    *(uint4*)&as[row * 64 + ch * 8] = h;
  }
}

// ---- GEMM ------------------------------------------------------------------
// 256 threads = 4 waves (2x2), each wave owns 64x64 = 4x4 frags of 16x16.
// Single-buffered 32KB LDS + natural VGPR (~112) -> 4 blocks/CU capacity;
// grid 688 fully resident in ONE round (90% fill). Cross-block overlap hides
// the per-block stage->compute chain (m114). Next-tile B loads issued right
// after the stage barrier (T14): the next top-of-loop barrier is the late wait.
template <bool USE_WS, bool SPLIT>
__global__ __launch_bounds__(256)
void qgemm(const uint16_t* __restrict__ xb, const float* __restrict__ xf,
           const int* __restrict__ qw, const float* __restrict__ scale,
           const float* __restrict__ bias, float* __restrict__ out,
           float* __restrict__ part) {
  __shared__ uint16_t As[BM * BK];  // 16KB
  __shared__ uint16_t Bs[BN * BK];  // 16KB

  const int tid = threadIdx.x;
  const int lane = tid & 63;
  const int wid = tid >> 6;
  const int wm = wid >> 1, wn = wid & 1;

  // XCD-aware mapping (bijective: grid % 8 == 0 in both modes).
  int nt, mt, ks;
  if constexpr (SPLIT) {
    // grid 688 = 8 * 86; 8 consecutive g's = one W panel (4 mt x 2 ks) per XCD
    const int xcd = blockIdx.x & 7;
    const int g = xcd * 86 + (blockIdx.x >> 3);
    nt = g >> 3;
    const int r = g & 7;
    ks = r >> 2;
    mt = r & 3;
  } else {
    // grid 344 = 8 * 43
    const int xcd = blockIdx.x & 7;
    const int g = xcd * 43 + (blockIdx.x >> 3);
    nt = g >> 2;
    mt = g & 3;
    ks = 0;
  }
  const int bm0 = mt * BM, bn0 = nt * BN;
  const int kbase0 = ks * KSPLIT_LEN;
  const int NIT = SPLIT ? (KSPLIT_LEN / BK) : (K_IN / BK);

  f32x4 acc[4][4] = {};
  int4 wreg[8];

  // prologue: issue B loads for tile 0
  b_load(qw, bn0, kbase0, tid, wreg);

  for (int t = 0; t < NIT; ++t) {
    const int kb = kbase0 + t * BK;
    // top barrier: (a) WAR - all waves done reading LDS from iter t-1;
    // (b) late wait for b_load(t) issued under iter t-1's compute.
    if (t) __syncthreads();

    // ---- stage phase ----
    if constexpr (USE_WS) {
      a_gload(xb, bm0, kb, As, wid, lane);
    } else {
      a_stage_f32(xf, bm0, kb, tid, As);
    }
    b_write(Bs, wreg, tid);  // convert + LDS write (wreg loads already landed)
    __syncthreads();         // drains a_gload (vmcnt) + ds writes (lgkm)

    // T14: issue next tile's B loads; latency hides under the MFMA phase
    if (t + 1 < NIT) b_load(qw, bn0, kb + BK, tid, wreg);

    // ---- compute phase ----
    const int kq = lane >> 4;
#pragma unroll
    for (int kk = 0; kk < 2; ++kk) {
      bf16x8 a[4], b[4];
#pragma unroll
      for (int mi = 0; mi < 4; ++mi) {
        int row = wm * 64 + mi * 16 + (lane & 15);
        int ch = (kk * 4 + kq) ^ (row & 7);
        a[mi] = *(const bf16x8*)&As[row * 64 + ch * 8];
      }
#pragma unroll
      for (int ni = 0; ni < 4; ++ni) {
        int row = wn * 64 + ni * 16 + (lane & 15);
        int ch = (kk * 4 + kq) ^ (row & 7);
        b[ni] = *(const bf16x8*)&Bs[row * 64 + ch * 8];
      }
      __builtin_amdgcn_s_setprio(1);
#pragma unroll
      for (int mi = 0; mi < 4; ++mi)
#pragma unroll
        for (int ni = 0; ni < 4; ++ni)
          acc[mi][ni] = __builtin_amdgcn_mfma_f32_16x16x32_bf16(a[mi], b[ni], acc[mi][ni], 0, 0, 0);
      __builtin_amdgcn_s_setprio(0);
    }
  }

  // ---- epilogue ----
  float* dst = out;
  float badd = 1.0f;
  if constexpr (SPLIT) {
    if (ks == 1) { dst = part; badd = 0.0f; }
  }
  const int kq = lane >> 4;
#pragma unroll
  for (int ni = 0; ni < 4; ++ni) {
    int col = bn0 + wn * 64 + ni * 16 + (lane & 15);
    float sc = scale[col];
    float bi = bias[col] * badd;
#pragma unroll
    for (int mi = 0; mi < 4; ++mi) {
      int rowb = bm0 + wm * 64 + mi * 16 + kq * 4;
#pragma unroll
      for (int r = 0; r < 4; ++r) {
        dst[(size_t)(rowb + r) * N_OUT + col] = acc[mi][ni][r] * sc + bi;
      }
    }
  }
}

// ---- launch ----------------------------------------------------------------
extern "C" void kernel_launch(void* const* d_in, const int* in_sizes, int n_in,
                              void* d_out, int out_size, void* d_ws, size_t ws_size,
                              hipStream_t stream) {
  const float* x = (const float*)d_in[0];
  const int* qw = (const int*)d_in[1];
  const float* scale = (const float*)d_in[2];
  const float* bias = (const float*)d_in[3];
  float* out = (float*)d_out;

  const size_t xb_bytes = (size_t)M_TOK * K_IN * sizeof(uint16_t);   // 4 MB
  const size_t part_bytes = (size_t)M_TOK * N_OUT * sizeof(float);   // 22.5 MB
  const int n4 = M_TOK * N_OUT / 4;

  if (ws_size >= xb_bytes + part_bytes) {
    uint16_t* xb = (uint16_t*)d_ws;
    float* part = (float*)((char*)d_ws + xb_bytes);
    xcvt_kernel<<<1024, 256, 0, stream>>>((const float4*)x, (uint4*)xb);
    qgemm<true, true><<<dim3(688), dim3(256), 0, stream>>>(xb, x, qw, scale, bias, out, part);
    reduce_kernel<<<dim3(2048), dim3(256), 0, stream>>>((float4*)out, (const float4*)part, n4);
  } else if (ws_size >= xb_bytes) {
    uint16_t* xb = (uint16_t*)d_ws;
    xcvt_kernel<<<1024, 256, 0, stream>>>((const float4*)x, (uint4*)xb);
    qgemm<true, false><<<dim3(344), dim3(256), 0, stream>>>(xb, x, qw, scale, bias, out, nullptr);
  } else {
    qgemm<false, false><<<dim3(344), dim3(256), 0, stream>>>(nullptr, x, qw, scale, bias, out, nullptr);
  }
}